// Round 1
// baseline (222.046 us; speedup 1.0000x reference)
//
#include <hip/hip_runtime.h>

// Problem constants (B=64, T=4096, D=100, K=4, BETA=0.25)
#define D_DIM   100
#define K_CODES 4
#define RPB     64      // rows per block
#define TPB     256     // threads per block (4 waves)
#define PITCH   65      // LDS transposed-tile pitch (words): gcd-safe vs 32 banks
#define N_ROWS  262144  // B*T

// Main fused kernel: Linear+ReLU, VQ distances (f64), argmin, aux gather, loss partials.
// Block = 64 rows. lane = row-in-block, wave = role (25-col strip for GEMM; code k for dist).
__global__ __launch_bounds__(TPB) void vq_main_kernel(
    const float* __restrict__ x, const float* __restrict__ W1,
    const float* __restrict__ b1, const float* __restrict__ cb,
    const int* __restrict__ qflag,
    float* __restrict__ out_h, float* __restrict__ out_pay,
    float* __restrict__ out_aux, double* __restrict__ partials)
{
    __shared__ float tile[D_DIM][PITCH];   // x^T then h^T: tile[d][r]
    __shared__ double d2s[K_CODES][RPB];
    __shared__ int    idxs[RPB];
    __shared__ double wred[4];

    const int tid  = threadIdx.x;
    const int lane = tid & 63;
    const int wave = tid >> 6;
    const int blk  = blockIdx.x;
    const int rowBase = blk * RPB;
    const float* xg = x + (size_t)rowBase * D_DIM;

    // ---- stage x tile transposed into LDS (coalesced float4 global reads) ----
    for (int v = tid; v < (RPB * D_DIM) / 4; v += TPB) {
        float4 val = reinterpret_cast<const float4*>(xg)[v];
        int flat = v * 4;
        int r = flat / D_DIM;
        int d = flat % D_DIM;          // 100 % 4 == 0 -> float4 never crosses rows
        tile[d + 0][r] = val.x;
        tile[d + 1][r] = val.y;
        tile[d + 2][r] = val.z;
        tile[d + 3][r] = val.w;
    }
    __syncthreads();

    // ---- GEMM: h[r][e] = relu(sum_d x[r][d]*W1[e][d] + b1[e]) ----
    // wave w owns e in [w*25, w*25+25); force scalar base so W1/b1 go through s_load.
    const int e0 = __builtin_amdgcn_readfirstlane(wave * 25);
    float acc[25];
    #pragma unroll
    for (int j = 0; j < 25; ++j) acc[j] = 0.0f;

    #pragma unroll
    for (int d0 = 0; d0 < D_DIM; d0 += 20) {
        float xv[20];
        #pragma unroll
        for (int dd = 0; dd < 20; ++dd) xv[dd] = tile[d0 + dd][lane];  // 2-way max, free
        #pragma unroll
        for (int j = 0; j < 25; ++j) {
            const float* wr = W1 + (e0 + j) * D_DIM + d0;   // scalar address -> s_load
            #pragma unroll
            for (int dd = 0; dd < 20; ++dd)
                acc[j] = fmaf(xv[dd], wr[dd], acc[j]);
        }
    }
    #pragma unroll
    for (int j = 0; j < 25; ++j)
        acc[j] = fmaxf(acc[j] + b1[e0 + j], 0.0f);

    __syncthreads();                       // everyone done reading x from tile
    #pragma unroll
    for (int j = 0; j < 25; ++j)
        tile[e0 + j][lane] = acc[j];       // store h^T (lanes consecutive -> conflict-free)
    __syncthreads();

    // ---- write h out (coalesced float4) ----
    {
        float* hg = out_h + (size_t)rowBase * D_DIM;
        for (int v = tid; v < (RPB * D_DIM) / 4; v += TPB) {
            int flat = v * 4;
            int r = flat / D_DIM;
            int d = flat % D_DIM;
            float4 val = make_float4(tile[d][r], tile[d+1][r], tile[d+2][r], tile[d+3][r]);
            reinterpret_cast<float4*>(hg)[v] = val;
        }
    }

    const int qz = *qflag;   // grid-uniform -> no divergence hazard around barriers
    if (qz) {
        // ---- distances: wave = code k, lane = row; f64 accumulation ----
        {
            const int k = __builtin_amdgcn_readfirstlane(wave % K_CODES);
            const float* crow = cb + k * D_DIM;             // scalar base -> s_load
            double s = 0.0;
            #pragma unroll
            for (int d = 0; d < D_DIM; ++d) {
                double dh = (double)tile[d][lane] - (double)crow[d];
                s = fma(dh, dh, s);
            }
            d2s[k][lane] = s;
        }
        __syncthreads();

        // ---- argmin (first-min tie-break, same as jnp.argmin) ----
        if (wave == 0) {
            double best = d2s[0][lane];
            int bi = 0;
            #pragma unroll
            for (int k2 = 1; k2 < K_CODES; ++k2) {
                double v = d2s[k2][lane];
                if (v < best) { best = v; bi = k2; }
            }
            idxs[lane] = bi;
            out_pay[rowBase + lane] = (float)bi;            // coalesced
        }
        __syncthreads();

        // ---- aux = codebook[idx] (coalesced float4 writes) + loss partial ----
        float* ag = out_aux + (size_t)rowBase * D_DIM;
        double ls = 0.0;
        for (int v = tid; v < (RPB * D_DIM) / 4; v += TPB) {
            int flat = v * 4;
            int r = flat / D_DIM;
            int d = flat % D_DIM;
            int bi = idxs[r];
            // cb + bi*100 + d is 16B-aligned (400B rows, d%4==0)
            float4 q4 = reinterpret_cast<const float4*>(cb + bi * D_DIM + d)[0];
            reinterpret_cast<float4*>(ag)[v] = q4;
            double e0d = (double)tile[d + 0][r] - (double)q4.x; ls = fma(e0d, e0d, ls);
            double e1d = (double)tile[d + 1][r] - (double)q4.y; ls = fma(e1d, e1d, ls);
            double e2d = (double)tile[d + 2][r] - (double)q4.z; ls = fma(e2d, e2d, ls);
            double e3d = (double)tile[d + 3][r] - (double)q4.w; ls = fma(e3d, e3d, ls);
        }
        // deterministic block reduction: wave shuffle tree, then 4 partials via LDS
        for (int off = 32; off > 0; off >>= 1)
            ls += __shfl_down(ls, off);
        if (lane == 0) wred[wave] = ls;
        __syncthreads();
        if (tid == 0)
            partials[blk] = wred[0] + wred[1] + wred[2] + wred[3];
    } else {
        // quantize==0 path (not exercised by harness inputs, kept for determinism)
        if (wave == 0) out_pay[rowBase + lane] = 0.0f;
        float* ag = out_aux + (size_t)rowBase * D_DIM;
        for (int v = tid; v < (RPB * D_DIM) / 4; v += TPB)
            reinterpret_cast<float4*>(ag)[v] = make_float4(0, 0, 0, 0);
        if (tid == 0) partials[blk] = 0.0;
    }
}

// Deterministic final reduce of per-block loss partials -> vq_loss scalar.
__global__ __launch_bounds__(256) void vq_final_kernel(
    const double* __restrict__ partials, int n, float* __restrict__ loss_out)
{
    __shared__ double sm[256];
    int tid = threadIdx.x;
    double s = 0.0;
    for (int i = tid; i < n; i += 256) s += partials[i];   // fixed order per thread
    sm[tid] = s;
    __syncthreads();
    for (int off = 128; off > 0; off >>= 1) {
        if (tid < off) sm[tid] += sm[tid + off];
        __syncthreads();
    }
    if (tid == 0) {
        double mse = sm[0] / ((double)N_ROWS * (double)D_DIM);
        loss_out[0] = (float)(1.25 * mse);   // (1 + BETA) * mean((h-q)^2)
    }
}

extern "C" void kernel_launch(void* const* d_in, const int* in_sizes, int n_in,
                              void* d_out, int out_size, void* d_ws, size_t ws_size,
                              hipStream_t stream) {
    const float* x  = (const float*)d_in[0];
    const float* W1 = (const float*)d_in[1];
    const float* b1 = (const float*)d_in[2];
    const float* cb = (const float*)d_in[3];
    const int* qflag = (const int*)d_in[4];

    float* out = (float*)d_out;
    const int NR = in_sizes[0] / D_DIM;        // 262144 rows
    const int nblocks = NR / RPB;              // 4096

    float* out_h    = out;                                  // [NR*100]
    float* out_pay  = out + (size_t)NR * D_DIM;             // [NR]
    float* out_aux  = out_pay + NR;                         // [NR*100]
    float* out_loss = out_aux + (size_t)NR * D_DIM;         // [1]
    double* partials = (double*)d_ws;                       // nblocks doubles

    vq_main_kernel<<<nblocks, TPB, 0, stream>>>(x, W1, b1, cb, qflag,
                                                out_h, out_pay, out_aux, partials);
    vq_final_kernel<<<1, 256, 0, stream>>>(partials, nblocks, out_loss);
}

// Round 3
// 221.884 us; speedup vs baseline: 1.0007x; 1.0007x over previous
//
#include <hip/hip_runtime.h>

// Problem constants (B=64, T=4096, D=100, K=4, BETA=0.25)
#define D_DIM   100
#define K_CODES 4
#define RPB     64      // rows per block
#define TPB     256     // threads per block (4 waves)
#define PITCH   67      // LDS tile pitch (words); 67%32=3 -> spreads strided access over banks
#define N_ROWS  262144  // B*T

// Fused: Linear+ReLU, VQ d2 partials (f64, R1-proven formulation) folded into GEMM
// epilogue, argmin, h+aux writeout, loss partial.
// Block = 64 rows (lane = row). Wave w owns e-strip [25w, 25w+25).
__global__ __launch_bounds__(TPB) void vq_main_kernel(
    const float* __restrict__ x, const float* __restrict__ W1,
    const float* __restrict__ b1, const float* __restrict__ cb,
    const int* __restrict__ qflag,
    float* __restrict__ out_h, float* __restrict__ out_pay,
    float* __restrict__ out_aux, double* __restrict__ partials)
{
    __shared__ float  tile[D_DIM][PITCH];      // x^T then h^T: tile[d][lane_row]
    __shared__ double pdd[4][K_CODES][RPB];    // [wave][code][row] f64 d2 partials
    __shared__ int    idxs[RPB];

    const int tid  = threadIdx.x;
    const int lane = tid & 63;
    const int wave = tid >> 6;
    const int blk  = blockIdx.x;
    const int rowBase = blk * RPB;
    const float* xg = x + (size_t)rowBase * D_DIM;

    // ---- stage x^T into LDS (coalesced float4 global reads) ----
    for (int v = tid; v < (RPB * D_DIM) / 4; v += TPB) {
        float4 val = reinterpret_cast<const float4*>(xg)[v];
        int r = v / 25;            // = 4v/100
        int d = (v % 25) * 4;      // 100%4==0 -> float4 never crosses rows
        tile[d + 0][r] = val.x;
        tile[d + 1][r] = val.y;
        tile[d + 2][r] = val.z;
        tile[d + 3][r] = val.w;
    }
    __syncthreads();

    // ---- GEMM: h[r][e] = relu(sum_d x[r][d]*W1[e][d] + b1[e]) ----
    const int e0 = __builtin_amdgcn_readfirstlane(wave * 25);
    float acc[25];
    #pragma unroll
    for (int j = 0; j < 25; ++j) acc[j] = b1[e0 + j];   // bias folded into init

    #pragma unroll
    for (int d0 = 0; d0 < D_DIM; d0 += 20) {
        float xv[20];
        #pragma unroll
        for (int dd = 0; dd < 20; ++dd) xv[dd] = tile[d0 + dd][lane];  // 2-way, free
        #pragma unroll
        for (int j = 0; j < 25; ++j) {
            const float* wr = W1 + (e0 + j) * D_DIM + d0;   // uniform -> s_load
            #pragma unroll
            for (int dd = 0; dd < 20; ++dd)
                acc[j] = fmaf(xv[dd], wr[dd], acc[j]);
        }
    }
    #pragma unroll
    for (int j = 0; j < 25; ++j)
        acc[j] = fmaxf(acc[j], 0.0f);

    const int qz = *qflag;   // grid-uniform

    if (qz) {
        // ---- fused VQ d2 strip-partials, f64 per-dim (identical arithmetic to R1,
        //      which produced zero argmin flips vs the numpy reference) ----
        double sc[K_CODES] = {0.0, 0.0, 0.0, 0.0};
        #pragma unroll
        for (int j = 0; j < 25; ++j) {
            double a = (double)acc[j];
            #pragma unroll
            for (int k = 0; k < K_CODES; ++k) {
                double c = (double)cb[k * D_DIM + e0 + j];  // uniform -> s_load
                double dh = a - c;
                sc[k] = fma(dh, dh, sc[k]);
            }
        }
        #pragma unroll
        for (int k = 0; k < K_CODES; ++k) pdd[wave][k][lane] = sc[k];

        __syncthreads();   // (2) x-reads done everywhere; pdd complete

        // ---- all waves: store h^T strip (conflict-free: lanes consecutive) ----
        #pragma unroll
        for (int j = 0; j < 25; ++j)
            tile[e0 + j][lane] = acc[j];

        // ---- wave 0 (concurrent with other waves' tile writes): argmin + loss ----
        if (wave == 0) {
            double d2[K_CODES];
            #pragma unroll
            for (int k = 0; k < K_CODES; ++k)
                d2[k] = (pdd[0][k][lane] + pdd[1][k][lane])
                      + (pdd[2][k][lane] + pdd[3][k][lane]);
            double best = d2[0];
            int bi = 0;
            #pragma unroll
            for (int k = 1; k < K_CODES; ++k)
                if (d2[k] < best) { best = d2[k]; bi = k; }   // first-min tie-break
            idxs[lane] = bi;
            out_pay[rowBase + lane] = (float)bi;

            double d2min = best;                  // = ||h - c_bi||^2
            for (int off = 32; off > 0; off >>= 1)
                d2min += __shfl_down(d2min, off);
            if (lane == 0) partials[blk] = d2min;
        }
        __syncthreads();   // (3) tile holds h^T; idxs ready

        // ---- combined writeout: h (LDS transpose read) + aux (codebook gather) ----
        float* hg = out_h + (size_t)rowBase * D_DIM;
        float* ag = out_aux + (size_t)rowBase * D_DIM;
        for (int v = tid; v < (RPB * D_DIM) / 4; v += TPB) {
            int r = v / 25;
            int d = (v % 25) * 4;
            float4 hv = make_float4(tile[d][r], tile[d+1][r], tile[d+2][r], tile[d+3][r]);
            reinterpret_cast<float4*>(hg)[v] = hv;
            int bi = idxs[r];
            float4 q4 = reinterpret_cast<const float4*>(cb + bi * D_DIM + d)[0];
            reinterpret_cast<float4*>(ag)[v] = q4;
        }
    } else {
        // quantize==0 path (not exercised; deterministic)
        __syncthreads();
        #pragma unroll
        for (int j = 0; j < 25; ++j)
            tile[e0 + j][lane] = acc[j];
        if (wave == 0) {
            out_pay[rowBase + lane] = 0.0f;
            if (lane == 0) partials[blk] = 0.0;
        }
        __syncthreads();
        float* hg = out_h + (size_t)rowBase * D_DIM;
        float* ag = out_aux + (size_t)rowBase * D_DIM;
        for (int v = tid; v < (RPB * D_DIM) / 4; v += TPB) {
            int r = v / 25;
            int d = (v % 25) * 4;
            float4 hv = make_float4(tile[d][r], tile[d+1][r], tile[d+2][r], tile[d+3][r]);
            reinterpret_cast<float4*>(hg)[v] = hv;
            reinterpret_cast<float4*>(ag)[v] = make_float4(0, 0, 0, 0);
        }
    }
}

// Deterministic final reduce of per-block loss partials -> vq_loss scalar.
__global__ __launch_bounds__(256) void vq_final_kernel(
    const double* __restrict__ partials, int n, float* __restrict__ loss_out)
{
    __shared__ double sm[256];
    int tid = threadIdx.x;
    double s = 0.0;
    for (int i = tid; i < n; i += 256) s += partials[i];
    sm[tid] = s;
    __syncthreads();
    for (int off = 128; off > 0; off >>= 1) {
        if (tid < off) sm[tid] += sm[tid + off];
        __syncthreads();
    }
    if (tid == 0) {
        double mse = sm[0] / ((double)N_ROWS * (double)D_DIM);
        loss_out[0] = (float)(1.25 * mse);   // (1 + BETA) * mean((h-q)^2)
    }
}

extern "C" void kernel_launch(void* const* d_in, const int* in_sizes, int n_in,
                              void* d_out, int out_size, void* d_ws, size_t ws_size,
                              hipStream_t stream) {
    const float* x  = (const float*)d_in[0];
    const float* W1 = (const float*)d_in[1];
    const float* b1 = (const float*)d_in[2];
    const float* cb = (const float*)d_in[3];
    const int* qflag = (const int*)d_in[4];

    float* out = (float*)d_out;
    const int NR = in_sizes[0] / D_DIM;        // 262144 rows
    const int nblocks = NR / RPB;              // 4096

    float* out_h    = out;                                  // [NR*100]
    float* out_pay  = out + (size_t)NR * D_DIM;             // [NR]
    float* out_aux  = out_pay + NR;                         // [NR*100]
    float* out_loss = out_aux + (size_t)NR * D_DIM;         // [1]
    double* partials = (double*)d_ws;                       // nblocks doubles

    vq_main_kernel<<<nblocks, TPB, 0, stream>>>(x, W1, b1, cb, qflag,
                                                out_h, out_pay, out_aux, partials);
    vq_final_kernel<<<1, 256, 0, stream>>>(partials, nblocks, out_loss);
}

// Round 4
// 200.001 us; speedup vs baseline: 1.1102x; 1.1094x over previous
//
#include <hip/hip_runtime.h>

// Problem constants (B=64, T=4096, D=100, K=4, BETA=0.25)
#define D_DIM   100
#define K_CODES 4
#define RPB     64      // rows per block
#define TPB     256     // threads per block (4 waves)
#define PITCH   65      // LDS tile pitch (words)
#define N_ROWS  262144  // B*T

// ---------------- Kernel A: Linear(100,100) + ReLU -> out_h ----------------
// LDS = x-tile only (26.0 KB) -> 6 blocks/CU, 24 waves/CU (75% occupancy).
__global__ __launch_bounds__(TPB) void gemm_relu_kernel(
    const float* __restrict__ x, const float* __restrict__ W1,
    const float* __restrict__ b1, float* __restrict__ out_h)
{
    __shared__ float tile[D_DIM][PITCH];   // x^T then h^T: tile[d][row]
    const int tid  = threadIdx.x;
    const int lane = tid & 63;
    const int wave = tid >> 6;
    const int rowBase = blockIdx.x * RPB;
    const float* xg = x + (size_t)rowBase * D_DIM;

    // stage x^T (coalesced float4 reads)
    for (int v = tid; v < (RPB * D_DIM) / 4; v += TPB) {
        float4 val = reinterpret_cast<const float4*>(xg)[v];
        int r = v / 25;            // 4v/100
        int d = (v % 25) * 4;      // float4 never crosses rows
        tile[d + 0][r] = val.x;
        tile[d + 1][r] = val.y;
        tile[d + 2][r] = val.z;
        tile[d + 3][r] = val.w;
    }
    __syncthreads();

    // GEMM: wave w owns e-strip [25w, 25w+25); lane = row
    const int e0 = __builtin_amdgcn_readfirstlane(wave * 25);
    float acc[25];
    #pragma unroll
    for (int j = 0; j < 25; ++j) acc[j] = b1[e0 + j];

    #pragma unroll
    for (int d0 = 0; d0 < D_DIM; d0 += 20) {
        float xv[20];
        #pragma unroll
        for (int dd = 0; dd < 20; ++dd) xv[dd] = tile[d0 + dd][lane];  // conflict-free
        #pragma unroll
        for (int j = 0; j < 25; ++j) {
            const float* wr = W1 + (e0 + j) * D_DIM + d0;   // uniform -> s_load
            #pragma unroll
            for (int dd = 0; dd < 20; ++dd)
                acc[j] = fmaf(xv[dd], wr[dd], acc[j]);
        }
    }

    __syncthreads();   // all x reads done before overwriting tile
    #pragma unroll
    for (int j = 0; j < 25; ++j)
        tile[e0 + j][lane] = fmaxf(acc[j], 0.0f);   // h^T, conflict-free
    __syncthreads();

    // coalesced h writeout
    float* hg = out_h + (size_t)rowBase * D_DIM;
    for (int v = tid; v < (RPB * D_DIM) / 4; v += TPB) {
        int r = v / 25;
        int d = (v % 25) * 4;
        reinterpret_cast<float4*>(hg)[v] =
            make_float4(tile[d][r], tile[d+1][r], tile[d+2][r], tile[d+3][r]);
    }
}

// ---------------- Kernel B: VQ distances/argmin/aux/loss ----------------
// Reads h (L3-hot). f64 per-dim distances (R1-proven, zero argmin flips).
__global__ __launch_bounds__(TPB) void vq_kernel(
    const float* __restrict__ h, const float* __restrict__ cb,
    const int* __restrict__ qflag,
    float* __restrict__ out_pay, float* __restrict__ out_aux,
    double* __restrict__ partials)
{
    __shared__ float  tile[D_DIM][PITCH];
    __shared__ double d2s[K_CODES][RPB];
    __shared__ int    idxs[RPB];
    const int tid  = threadIdx.x;
    const int lane = tid & 63;
    const int wave = tid >> 6;
    const int blk  = blockIdx.x;
    const int rowBase = blk * RPB;
    const int qz = *qflag;   // grid-uniform

    if (qz) {
        const float* hgc = h + (size_t)rowBase * D_DIM;
        for (int v = tid; v < (RPB * D_DIM) / 4; v += TPB) {
            float4 val = reinterpret_cast<const float4*>(hgc)[v];
            int r = v / 25;
            int d = (v % 25) * 4;
            tile[d + 0][r] = val.x;
            tile[d + 1][r] = val.y;
            tile[d + 2][r] = val.z;
            tile[d + 3][r] = val.w;
        }
        __syncthreads();

        // wave = code k, lane = row; f64 accumulation (R1 formulation)
        {
            const int k = __builtin_amdgcn_readfirstlane(wave & 3);
            const float* crow = cb + k * D_DIM;            // uniform -> s_load
            double s = 0.0;
            #pragma unroll
            for (int d = 0; d < D_DIM; ++d) {
                double dh = (double)tile[d][lane] - (double)crow[d];
                s = fma(dh, dh, s);
            }
            d2s[k][lane] = s;
        }
        __syncthreads();

        // wave 0: argmin (first-min tie-break) + loss partial
        if (wave == 0) {
            double best = d2s[0][lane];
            int bi = 0;
            #pragma unroll
            for (int k = 1; k < K_CODES; ++k) {
                double v = d2s[k][lane];
                if (v < best) { best = v; bi = k; }
            }
            idxs[lane] = bi;
            out_pay[rowBase + lane] = (float)bi;
            double d2min = best;                 // = ||h - c_bi||^2
            for (int off = 32; off > 0; off >>= 1)
                d2min += __shfl_down(d2min, off);
            if (lane == 0) partials[blk] = d2min;
        }
        __syncthreads();

        // aux = codebook[idx], coalesced float4 writes
        float* ag = out_aux + (size_t)rowBase * D_DIM;
        for (int v = tid; v < (RPB * D_DIM) / 4; v += TPB) {
            int r = v / 25;
            int d = (v % 25) * 4;
            int bi = idxs[r];
            reinterpret_cast<float4*>(ag)[v] =
                reinterpret_cast<const float4*>(cb + bi * D_DIM + d)[0];
        }
    } else {
        // quantize==0 path (not exercised; deterministic)
        if (wave == 0) {
            out_pay[rowBase + lane] = 0.0f;
            if (lane == 0) partials[blk] = 0.0;
        }
        float* ag = out_aux + (size_t)rowBase * D_DIM;
        for (int v = tid; v < (RPB * D_DIM) / 4; v += TPB)
            reinterpret_cast<float4*>(ag)[v] = make_float4(0, 0, 0, 0);
    }
}

// ---------------- deterministic final loss reduce ----------------
__global__ __launch_bounds__(256) void vq_final_kernel(
    const double* __restrict__ partials, int n, float* __restrict__ loss_out)
{
    __shared__ double sm[256];
    int tid = threadIdx.x;
    double s = 0.0;
    for (int i = tid; i < n; i += 256) s += partials[i];
    sm[tid] = s;
    __syncthreads();
    for (int off = 128; off > 0; off >>= 1) {
        if (tid < off) sm[tid] += sm[tid + off];
        __syncthreads();
    }
    if (tid == 0) {
        double mse = sm[0] / ((double)N_ROWS * (double)D_DIM);
        loss_out[0] = (float)(1.25 * mse);   // (1 + BETA) * mean((h-q)^2)
    }
}

extern "C" void kernel_launch(void* const* d_in, const int* in_sizes, int n_in,
                              void* d_out, int out_size, void* d_ws, size_t ws_size,
                              hipStream_t stream) {
    const float* x  = (const float*)d_in[0];
    const float* W1 = (const float*)d_in[1];
    const float* b1 = (const float*)d_in[2];
    const float* cb = (const float*)d_in[3];
    const int* qflag = (const int*)d_in[4];

    float* out = (float*)d_out;
    const int NR = in_sizes[0] / D_DIM;        // 262144 rows
    const int nblocks = NR / RPB;              // 4096

    float* out_h    = out;                                  // [NR*100]
    float* out_pay  = out + (size_t)NR * D_DIM;             // [NR]
    float* out_aux  = out_pay + NR;                         // [NR*100]
    float* out_loss = out_aux + (size_t)NR * D_DIM;         // [1]
    double* partials = (double*)d_ws;                       // nblocks doubles

    gemm_relu_kernel<<<nblocks, TPB, 0, stream>>>(x, W1, b1, out_h);
    vq_kernel<<<nblocks, TPB, 0, stream>>>(out_h, cb, qflag,
                                           out_pay, out_aux, partials);
    vq_final_kernel<<<1, 256, 0, stream>>>(partials, nblocks, out_loss);
}

// Round 6
// 145.142 us; speedup vs baseline: 1.5299x; 1.3780x over previous
//
#include <hip/hip_runtime.h>

// Problem constants (B=64, T=4096, D=100, K=4, BETA=0.25)
#define D_DIM   100
#define K_CODES 4
#define RPB     64      // rows per block
#define TPB     256     // threads per block (4 waves)
#define PITCH   65      // LDS pitch for VQ / fallback kernels
#define N_ROWS  262144  // B*T
#define KP      128     // padded K for MFMA (4 k-tiles of 32)
#define NP      128     // padded N rows of W hi/lo storage
#define TAU     0.25    // d2 margin below which we recompute exactly (>=10x error bound)

typedef __attribute__((ext_vector_type(8))) __bf16 bf16x8;
typedef __attribute__((ext_vector_type(4))) float  f32x4;

// float -> bf16 bits, round-to-nearest-even
__device__ __forceinline__ unsigned short f2bf_rne(float f) {
    unsigned int u = __builtin_bit_cast(unsigned int, f);
    unsigned int r = u + 0x7fffu + ((u >> 16) & 1u);
    return (unsigned short)(r >> 16);
}
__device__ __forceinline__ float bf2f(unsigned short b) {
    unsigned int u = ((unsigned int)b) << 16;
    return __builtin_bit_cast(float, u);
}

// ---------------- pre-kernel: split W1 into padded bf16 hi/lo [NP][KP] ----------------
__global__ __launch_bounds__(256) void split_w_kernel(
    const float* __restrict__ W1,
    unsigned short* __restrict__ Whi, unsigned short* __restrict__ Wlo)
{
    int i = blockIdx.x * 256 + threadIdx.x;
    if (i >= NP * KP) return;
    int n = i / KP, k = i % KP;
    float w = (n < D_DIM && k < D_DIM) ? W1[n * D_DIM + k] : 0.0f;
    unsigned short hb = f2bf_rne(w);
    float lo = w - bf2f(hb);
    Whi[i] = hb;
    Wlo[i] = f2bf_rne(lo);
}

// ---------------- Kernel A (MFMA): Linear(100,100)+ReLU via 3-pass split-bf16 ----------------
// Layout verified in R5 (h output passed). Block = 64 rows, 4 waves; wave owns 32 cols.
__global__ __launch_bounds__(TPB) void gemm_relu_mfma(
    const float* __restrict__ x,
    const unsigned short* __restrict__ Whi, const unsigned short* __restrict__ Wlo,
    const float* __restrict__ b1, float* __restrict__ out_h)
{
    __shared__ unsigned short xhi[RPB * KP];   // 16 KB, swizzled [row][k]
    __shared__ unsigned short xlo[RPB * KP];   // 16 KB
    const int tid  = threadIdx.x;
    const int lane = tid & 63;
    const int wave = tid >> 6;
    const int rowBase = blockIdx.x * RPB;
    const float* xg = x + (size_t)rowBase * D_DIM;

    // B fragments (registers) + bias
    const int bcol0 = wave * 32;
    const int bn  = lane & 15;
    const int bk  = (lane >> 4) * 8;
    bf16x8 bh[2][4], bl[2][4];
    #pragma unroll
    for (int ct = 0; ct < 2; ++ct) {
        int n = bcol0 + ct * 16 + bn;
        #pragma unroll
        for (int kt = 0; kt < 4; ++kt) {
            int off = n * KP + kt * 32 + bk;
            bh[ct][kt] = *reinterpret_cast<const bf16x8*>(Whi + off);
            bl[ct][kt] = *reinterpret_cast<const bf16x8*>(Wlo + off);
        }
    }
    float bias[2];
    #pragma unroll
    for (int ct = 0; ct < 2; ++ct) {
        int n = bcol0 + ct * 16 + bn;
        bias[ct] = (n < D_DIM) ? b1[n] : 0.0f;
    }

    // stage x: f32 coalesced load -> hi/lo bf16 -> swizzled LDS
    for (int v = tid; v < RPB * 25; v += TPB) {
        float4 val = reinterpret_cast<const float4*>(xg)[v];
        int r = v / 25;
        int d = (v % 25) * 4;
        ushort4 hw, lw;
        hw.x = f2bf_rne(val.x); lw.x = f2bf_rne(val.x - bf2f(hw.x));
        hw.y = f2bf_rne(val.y); lw.y = f2bf_rne(val.y - bf2f(hw.y));
        hw.z = f2bf_rne(val.z); lw.z = f2bf_rne(val.z - bf2f(hw.z));
        hw.w = f2bf_rne(val.w); lw.w = f2bf_rne(val.w - bf2f(hw.w));
        int byte = r * 256 + ((d * 2) ^ ((r & 7) << 4));
        *reinterpret_cast<ushort4*>(reinterpret_cast<char*>(xhi) + byte) = hw;
        *reinterpret_cast<ushort4*>(reinterpret_cast<char*>(xlo) + byte) = lw;
    }
    for (int v = tid; v < RPB * 7; v += TPB) {   // zero-pad k in [100,128)
        int r = v / 7;
        int c = v % 7;
        int byte = r * 256 + (((200 + c * 8)) ^ ((r & 7) << 4));
        ushort4 z = {0, 0, 0, 0};
        *reinterpret_cast<ushort4*>(reinterpret_cast<char*>(xhi) + byte) = z;
        *reinterpret_cast<ushort4*>(reinterpret_cast<char*>(xlo) + byte) = z;
    }
    __syncthreads();

    // MFMA main: 4 row-tiles x 2 col-tiles x 4 k-tiles x 3 passes
    const int am = lane & 15;
    const int ak = (lane >> 4) * 8;
    #pragma unroll
    for (int rt = 0; rt < 4; ++rt) {
        const int mrow = rt * 16 + am;
        bf16x8 ah[4], al[4];
        #pragma unroll
        for (int kt = 0; kt < 4; ++kt) {
            int byte = mrow * 256 + (((kt * 32 + ak) * 2) ^ ((mrow & 7) << 4));
            ah[kt] = *reinterpret_cast<const bf16x8*>(reinterpret_cast<const char*>(xhi) + byte);
            al[kt] = *reinterpret_cast<const bf16x8*>(reinterpret_cast<const char*>(xlo) + byte);
        }
        #pragma unroll
        for (int ct = 0; ct < 2; ++ct) {
            f32x4 acc = {0.f, 0.f, 0.f, 0.f};
            #pragma unroll
            for (int kt = 0; kt < 4; ++kt) {
                acc = __builtin_amdgcn_mfma_f32_16x16x32_bf16(ah[kt], bl[ct][kt], acc, 0, 0, 0);
                acc = __builtin_amdgcn_mfma_f32_16x16x32_bf16(al[kt], bh[ct][kt], acc, 0, 0, 0);
                acc = __builtin_amdgcn_mfma_f32_16x16x32_bf16(ah[kt], bh[ct][kt], acc, 0, 0, 0);
            }
            int n = bcol0 + ct * 16 + bn;
            if (n < D_DIM) {
                int rb = rt * 16 + (lane >> 4) * 4;
                #pragma unroll
                for (int i = 0; i < 4; ++i) {
                    float h = fmaxf(acc[i] + bias[ct], 0.0f);
                    out_h[(size_t)(rowBase + rb + i) * D_DIM + n] = h;
                }
            }
        }
    }
}

// ---------------- Kernel A fallback (R4 VALU path) ----------------
__global__ __launch_bounds__(TPB) void gemm_relu_valu(
    const float* __restrict__ x, const float* __restrict__ W1,
    const float* __restrict__ b1, float* __restrict__ out_h)
{
    __shared__ float tile[D_DIM][PITCH];
    const int tid  = threadIdx.x;
    const int lane = tid & 63;
    const int wave = tid >> 6;
    const int rowBase = blockIdx.x * RPB;
    const float* xg = x + (size_t)rowBase * D_DIM;

    for (int v = tid; v < (RPB * D_DIM) / 4; v += TPB) {
        float4 val = reinterpret_cast<const float4*>(xg)[v];
        int r = v / 25;
        int d = (v % 25) * 4;
        tile[d + 0][r] = val.x; tile[d + 1][r] = val.y;
        tile[d + 2][r] = val.z; tile[d + 3][r] = val.w;
    }
    __syncthreads();
    const int e0 = __builtin_amdgcn_readfirstlane(wave * 25);
    float acc[25];
    #pragma unroll
    for (int j = 0; j < 25; ++j) acc[j] = b1[e0 + j];
    #pragma unroll
    for (int d0 = 0; d0 < D_DIM; d0 += 20) {
        float xv[20];
        #pragma unroll
        for (int dd = 0; dd < 20; ++dd) xv[dd] = tile[d0 + dd][lane];
        #pragma unroll
        for (int j = 0; j < 25; ++j) {
            const float* wr = W1 + (e0 + j) * D_DIM + d0;
            #pragma unroll
            for (int dd = 0; dd < 20; ++dd)
                acc[j] = fmaf(xv[dd], wr[dd], acc[j]);
        }
    }
    __syncthreads();
    #pragma unroll
    for (int j = 0; j < 25; ++j)
        tile[e0 + j][lane] = fmaxf(acc[j], 0.0f);
    __syncthreads();
    float* hg = out_h + (size_t)rowBase * D_DIM;
    for (int v = tid; v < (RPB * D_DIM) / 4; v += TPB) {
        int r = v / 25;
        int d = (v % 25) * 4;
        reinterpret_cast<float4*>(hg)[v] =
            make_float4(tile[d][r], tile[d+1][r], tile[d+2][r], tile[d+3][r]);
    }
}

// ---------------- Kernel B: VQ with margin-guarded exact recompute ----------------
__global__ __launch_bounds__(TPB) void vq_kernel(
    const float* __restrict__ h, const float* __restrict__ x,
    const float* __restrict__ W1, const float* __restrict__ b1,
    const float* __restrict__ cb, const int* __restrict__ qflag,
    float* __restrict__ out_pay, float* __restrict__ out_aux,
    double* __restrict__ partials)
{
    __shared__ float  tile[D_DIM][PITCH];
    __shared__ double d2s[K_CODES][RPB];
    __shared__ int    idxs[RPB];
    __shared__ unsigned long long flagmask;
    const int tid  = threadIdx.x;
    const int lane = tid & 63;
    const int wave = tid >> 6;
    const int blk  = blockIdx.x;
    const int rowBase = blk * RPB;
    const int qz = *qflag;

    if (qz) {
        const float* hgc = h + (size_t)rowBase * D_DIM;
        for (int v = tid; v < (RPB * D_DIM) / 4; v += TPB) {
            float4 val = reinterpret_cast<const float4*>(hgc)[v];
            int r = v / 25;
            int d = (v % 25) * 4;
            tile[d + 0][r] = val.x; tile[d + 1][r] = val.y;
            tile[d + 2][r] = val.z; tile[d + 3][r] = val.w;
        }
        __syncthreads();
        {   // wave = code k, lane = row; f64 distance from (approximate) h
            const int k = __builtin_amdgcn_readfirstlane(wave & 3);
            const float* crow = cb + k * D_DIM;
            double s = 0.0;
            #pragma unroll
            for (int d = 0; d < D_DIM; ++d) {
                double dh = (double)tile[d][lane] - (double)crow[d];
                s = fma(dh, dh, s);
            }
            d2s[k][lane] = s;
        }
        __syncthreads();

        // wave 0: tentative argmin + margin flag
        if (wave == 0) {
            double best = d2s[0][lane], second = 1e300;
            int bi = 0;
            #pragma unroll
            for (int k = 1; k < K_CODES; ++k) {
                double v = d2s[k][lane];
                if (v < best) { second = best; best = v; bi = k; }
                else if (v < second) { second = v; }
            }
            idxs[lane] = bi;
            unsigned long long m = __ballot((second - best) < TAU);
            if (lane == 0) flagmask = m;
        }
        __syncthreads();

        // margin-flagged rows: wave-cooperative exact recompute (R1 arithmetic)
        {
            unsigned long long m = flagmask;
            int i = 0;
            while (m) {
                int r = __ffsll((long long)m) - 1;
                m &= m - 1;
                if ((i & 3) == wave) {
                    // exact f32 h for row r: lane -> cols {lane, lane+64}
                    const int e1 = lane;
                    const int e2 = 64 + lane;
                    const bool has2 = (e2 < D_DIM);
                    float z1 = b1[e1];
                    float z2 = has2 ? b1[e2] : 0.0f;
                    const float* xr  = x + (size_t)(rowBase + r) * D_DIM;
                    const float* w1r = W1 + e1 * D_DIM;
                    const float* w2r = W1 + (has2 ? e2 : 0) * D_DIM;
                    #pragma unroll
                    for (int d4 = 0; d4 < 25; ++d4) {
                        float4 xv = reinterpret_cast<const float4*>(xr)[d4];
                        float4 wa = reinterpret_cast<const float4*>(w1r)[d4];
                        z1 = fmaf(xv.x, wa.x, z1); z1 = fmaf(xv.y, wa.y, z1);
                        z1 = fmaf(xv.z, wa.z, z1); z1 = fmaf(xv.w, wa.w, z1);
                        float4 wb = reinterpret_cast<const float4*>(w2r)[d4];
                        z2 = fmaf(xv.x, wb.x, z2); z2 = fmaf(xv.y, wb.y, z2);
                        z2 = fmaf(xv.z, wb.z, z2); z2 = fmaf(xv.w, wb.w, z2);
                    }
                    float h1 = fmaxf(z1, 0.0f);
                    float h2 = fmaxf(z2, 0.0f);
                    double dk[K_CODES];
                    #pragma unroll
                    for (int k = 0; k < K_CODES; ++k) {
                        double p;
                        {
                            double dh = (double)h1 - (double)cb[k * D_DIM + e1];
                            p = dh * dh;
                        }
                        if (has2) {
                            double dh = (double)h2 - (double)cb[k * D_DIM + e2];
                            p = fma(dh, dh, p);
                        }
                        for (int off = 32; off > 0; off >>= 1)
                            p += __shfl_down(p, off);
                        dk[k] = p;
                    }
                    if (lane == 0) {
                        double best = dk[0];
                        int bi = 0;
                        #pragma unroll
                        for (int k = 1; k < K_CODES; ++k)
                            if (dk[k] < best) { best = dk[k]; bi = k; }
                        idxs[r] = bi;          // exact decision overrides
                    }
                }
                ++i;
            }
        }
        __syncthreads();

        // wave 0: final payload + loss partial (uses possibly-corrected idxs)
        if (wave == 0) {
            int bi = idxs[lane];
            out_pay[rowBase + lane] = (float)bi;
            double d2min = d2s[bi][lane];
            for (int off = 32; off > 0; off >>= 1)
                d2min += __shfl_down(d2min, off);
            if (lane == 0) partials[blk] = d2min;
        }

        // aux = codebook[idx], coalesced float4 writes
        float* ag = out_aux + (size_t)rowBase * D_DIM;
        for (int v = tid; v < (RPB * D_DIM) / 4; v += TPB) {
            int r = v / 25;
            int d = (v % 25) * 4;
            int bi = idxs[r];
            reinterpret_cast<float4*>(ag)[v] =
                reinterpret_cast<const float4*>(cb + bi * D_DIM + d)[0];
        }
    } else {
        if (wave == 0) {
            out_pay[rowBase + lane] = 0.0f;
            if (lane == 0) partials[blk] = 0.0;
        }
        float* ag = out_aux + (size_t)rowBase * D_DIM;
        for (int v = tid; v < (RPB * D_DIM) / 4; v += TPB)
            reinterpret_cast<float4*>(ag)[v] = make_float4(0, 0, 0, 0);
    }
}

// ---------------- deterministic final loss reduce ----------------
__global__ __launch_bounds__(256) void vq_final_kernel(
    const double* __restrict__ partials, int n, float* __restrict__ loss_out)
{
    __shared__ double sm[256];
    int tid = threadIdx.x;
    double s = 0.0;
    for (int i = tid; i < n; i += 256) s += partials[i];
    sm[tid] = s;
    __syncthreads();
    for (int off = 128; off > 0; off >>= 1) {
        if (tid < off) sm[tid] += sm[tid + off];
        __syncthreads();
    }
    if (tid == 0) {
        double mse = sm[0] / ((double)N_ROWS * (double)D_DIM);
        loss_out[0] = (float)(1.25 * mse);   // (1 + BETA) * mean((h-q)^2)
    }
}

extern "C" void kernel_launch(void* const* d_in, const int* in_sizes, int n_in,
                              void* d_out, int out_size, void* d_ws, size_t ws_size,
                              hipStream_t stream) {
    const float* x  = (const float*)d_in[0];
    const float* W1 = (const float*)d_in[1];
    const float* b1 = (const float*)d_in[2];
    const float* cb = (const float*)d_in[3];
    const int* qflag = (const int*)d_in[4];

    float* out = (float*)d_out;
    const int NR = in_sizes[0] / D_DIM;        // 262144 rows
    const int nblocks = NR / RPB;              // 4096

    float* out_h    = out;                                  // [NR*100]
    float* out_pay  = out + (size_t)NR * D_DIM;             // [NR]
    float* out_aux  = out_pay + NR;                         // [NR*100]
    float* out_loss = out_aux + (size_t)NR * D_DIM;         // [1]

    double* partials = (double*)d_ws;                       // 32 KB
    const size_t w_off = (size_t)nblocks * sizeof(double);
    unsigned short* Whi = (unsigned short*)((char*)d_ws + w_off);   // 32 KB
    unsigned short* Wlo = Whi + NP * KP;                            // 32 KB
    const size_t need = w_off + (size_t)2 * NP * KP * sizeof(unsigned short);

    if (ws_size >= need) {
        split_w_kernel<<<(NP * KP) / 256, 256, 0, stream>>>(W1, Whi, Wlo);
        gemm_relu_mfma<<<nblocks, TPB, 0, stream>>>(x, Whi, Wlo, b1, out_h);
    } else {
        gemm_relu_valu<<<nblocks, TPB, 0, stream>>>(x, W1, b1, out_h);
    }
    vq_kernel<<<nblocks, TPB, 0, stream>>>(out_h, x, W1, b1, cb, qflag,
                                           out_pay, out_aux, partials);
    vq_final_kernel<<<1, 256, 0, stream>>>(partials, nblocks, out_loss);
}